// Round 1
// baseline (38410.300 us; speedup 1.0000x reference)
//
#include <hip/hip_runtime.h>

#define NT 1024

#define FMA4(A_, S_, V_) do { (A_).x += (S_)*(V_).x; (A_).y += (S_)*(V_).y; \
                              (A_).z += (S_)*(V_).z; (A_).w += (S_)*(V_).w; } while(0)
#define SCL4(A_, S_) do { (A_).x = ((A_).x*(S_))*(S_); (A_).y = ((A_).y*(S_))*(S_); \
                          (A_).z = ((A_).z*(S_))*(S_); (A_).w = ((A_).w*(S_))*(S_); } while(0)

__device__ __forceinline__ float fast_sigmoid(float x) { return 1.f/(1.f + __expf(-x)); }
__device__ __forceinline__ float fast_tanh(float x) {
  float t = __expf(-2.f*fabsf(x));
  float y = (1.f - t)/(1.f + t);
  return copysignf(y, x);
}

// ~131.3 KB of LDS (fits 160 KB/CU on gfx950); spectral buffers overlay q/kT.
struct SmemScan {
  float h[53][128];     // GRU/attention state (h_out carry)
  float v[53][128];
  float S[53][56];      // scores, then attn (pad cols kept at 0)
  union {
    struct { float q[53][132]; float kT[128][60]; } a;
    struct { float G0[56][56]; float A[56][56]; float Bq[56][56];
             float pv[56]; float y1[56]; float y2[56]; } s;
  } u;
  float u384[384], v00[384], bhh[384];  // gi rank-1 vectors + b_hh
  float qb[128], kb[128], vb[128];
  float xt[56];
  float red[16];
  float sc_s;
  float sc_ev;
};

__global__ void __launch_bounds__(1024)
scan_kernel(const float* __restrict__ x, const float* __restrict__ emb_w,
            const float* __restrict__ emb_b, const float* __restrict__ w_ih,
            const float* __restrict__ w_hh, const float* __restrict__ b_ih,
            const float* __restrict__ b_hh, const float* __restrict__ q_w,
            const float* __restrict__ q_b, const float* __restrict__ k_w,
            const float* __restrict__ k_b, const float* __restrict__ v_w,
            const float* __restrict__ v_b, const float* __restrict__ gate_b,
            float* __restrict__ out_align)
{
  extern __shared__ char smem_raw[];
  SmemScan& sm = *reinterpret_cast<SmemScan*>(smem_raw);
  const int b = blockIdx.x;
  const int tid = threadIdx.x;

  // ---- one-time setup: u = emb_w@w_ih, v00 = emb_b@w_ih + b_ih ----
  for (int j = tid; j < 384; j += NT) {
    float su = 0.f, sv = 0.f;
    for (int m = 0; m < 64; ++m) {
      float w = w_ih[m*384 + j];
      su += emb_w[m]*w;
      sv += emb_b[m]*w;
    }
    sm.u384[j] = su;
    sm.v00[j]  = sv + b_ih[j];
    sm.bhh[j]  = b_hh[j];
  }
  for (int j = tid; j < 128; j += NT) { sm.qb[j] = q_b[j]; sm.kb[j] = k_b[j]; sm.vb[j] = v_b[j]; }
  for (int idx = tid; idx < 53*128; idx += NT) sm.h[idx >> 7][idx & 127] = 0.f;
  if (tid < 159) { int i = tid/3; int c = 53 + (tid - 3*i); sm.S[i][c] = 0.f; }  // zero S pad cols
  __syncthreads();

  const int f  = tid & 127;
  const int c0 = tid >> 7;       // 0..7
  int  cix[7]; bool cok[7];
  #pragma unroll
  for (int i = 0; i < 7; ++i) { int cc = c0 + 8*i; cok[i] = (cc < 53); cix[i] = cok[i] ? cc : 52; }

  for (int t = 0; t < 200; ++t) {
    if (tid < 53) sm.xt[tid] = x[(b*200 + t)*53 + tid];
    __syncthreads();   // B1: x visible, prev h writes visible

    // ---------- Phase 1: gh = h@w_hh, GRU gates -> h_new ----------
    float a0[7], a1[7], a2[7];
    #pragma unroll
    for (int i = 0; i < 7; ++i) { a0[i] = 0.f; a1[i] = 0.f; a2[i] = 0.f; }
    {
      const float* wr = w_hh + f;
      for (int fi = 0; fi < 128; ++fi) {
        float w0 = wr[fi*384];
        float w1 = wr[fi*384 + 128];
        float w2 = wr[fi*384 + 256];
        #pragma unroll
        for (int i = 0; i < 7; ++i) {
          float hv = sm.h[cix[i]][fi];   // LDS broadcast (wave-uniform addr)
          a0[i] += hv*w0; a1[i] += hv*w1; a2[i] += hv*w2;
        }
      }
    }
    float hnew[7];
    {
      float uf0 = sm.u384[f], uf1 = sm.u384[128+f], uf2 = sm.u384[256+f];
      float v0f0 = sm.v00[f], v0f1 = sm.v00[128+f], v0f2 = sm.v00[256+f];
      float bh0 = sm.bhh[f], bh1 = sm.bhh[128+f], bh2 = sm.bhh[256+f];
      #pragma unroll
      for (int i = 0; i < 7; ++i) {
        float xs = sm.xt[cix[i]];
        float ir = xs*uf0 + v0f0, iz = xs*uf1 + v0f1, in_ = xs*uf2 + v0f2;
        float hr = a0[i] + bh0, hz = a1[i] + bh1, hn = a2[i] + bh2;
        float r = fast_sigmoid(ir + hr);
        float z = fast_sigmoid(iz + hz);
        float n = fast_tanh(in_ + r*hn);
        hnew[i] = (1.f - z)*n + z*sm.h[cix[i]][f];
      }
    }
    __syncthreads();   // B2: everyone done reading old h
    #pragma unroll
    for (int i = 0; i < 7; ++i) if (cok[i]) sm.h[cix[i]][f] = hnew[i];
    __syncthreads();   // B3: h now holds h_new

    // ---------- Phase 2: q,k,v = h_new @ {q_w,k_w,v_w} + bias ----------
    float aq[7], ak[7], av[7];
    #pragma unroll
    for (int i = 0; i < 7; ++i) { aq[i] = 0.f; ak[i] = 0.f; av[i] = 0.f; }
    for (int fi = 0; fi < 128; ++fi) {
      float wq = q_w[fi*128 + f];
      float wk = k_w[fi*128 + f];
      float wv = v_w[fi*128 + f];
      #pragma unroll
      for (int i = 0; i < 7; ++i) {
        float hv = sm.h[cix[i]][fi];
        aq[i] += hv*wq; ak[i] += hv*wk; av[i] += hv*wv;
      }
    }
    {
      float bq = sm.qb[f], bk = sm.kb[f], bv = sm.vb[f];
      #pragma unroll
      for (int i = 0; i < 7; ++i) if (cok[i]) {
        sm.u.a.q[cix[i]][f]  = aq[i] + bq;
        sm.u.a.kT[f][cix[i]] = ak[i] + bk;
        sm.v[cix[i]][f]      = av[i] + bv;
      }
    }
    __syncthreads();   // B4

    // ---------- Phase 3: S = tanh(q @ k^T), 4x4 register tiles ----------
    if (tid < 196) {
      const int ig = tid/14, jg = tid - ig*14;
      const int i0 = ig*4, j0 = jg*4;
      float4 acc[4];
      #pragma unroll
      for (int r = 0; r < 4; ++r) { acc[r].x = acc[r].y = acc[r].z = acc[r].w = 0.f; }
      for (int fi = 0; fi < 128; fi += 4) {
        float4 kv0 = *(const float4*)&sm.u.a.kT[fi  ][j0];
        float4 kv1 = *(const float4*)&sm.u.a.kT[fi+1][j0];
        float4 kv2 = *(const float4*)&sm.u.a.kT[fi+2][j0];
        float4 kv3 = *(const float4*)&sm.u.a.kT[fi+3][j0];
        #pragma unroll
        for (int r = 0; r < 4; ++r) {
          int ii = i0 + r; ii = (ii < 53) ? ii : 52;
          float4 qv = *(const float4*)&sm.u.a.q[ii][fi];
          FMA4(acc[r], qv.x, kv0); FMA4(acc[r], qv.y, kv1);
          FMA4(acc[r], qv.z, kv2); FMA4(acc[r], qv.w, kv3);
        }
      }
      #pragma unroll
      for (int r = 0; r < 4; ++r) {
        int ii = i0 + r;
        if (ii < 53) {
          float avv[4] = {acc[r].x, acc[r].y, acc[r].z, acc[r].w};
          #pragma unroll
          for (int jj = 0; jj < 4; ++jj) {
            int j = j0 + jj;
            if (j < 53) sm.S[ii][j] = fast_tanh(avv[jj]);  // pad cols never written -> stay 0
          }
        }
      }
    }
    __syncthreads();   // B5

    // ---------- Spectral norm: G0 = S^T S; 7 normalized squarings; Rayleigh ----------
    if (tid < 196) {
      const int ig = tid/14, jg = tid - ig*14;
      const int i0 = ig*4, j0 = jg*4;
      float4 acc[4];
      #pragma unroll
      for (int r = 0; r < 4; ++r) { acc[r].x = acc[r].y = acc[r].z = acc[r].w = 0.f; }
      for (int m = 0; m < 53; ++m) {
        float4 si = *(const float4*)&sm.S[m][i0];
        float4 sj = *(const float4*)&sm.S[m][j0];
        FMA4(acc[0], si.x, sj); FMA4(acc[1], si.y, sj);
        FMA4(acc[2], si.z, sj); FMA4(acc[3], si.w, sj);
      }
      #pragma unroll
      for (int r = 0; r < 4; ++r) *(float4*)&sm.u.s.G0[i0+r][j0] = acc[r];
    }
    __syncthreads();
    {  // max-abs of G0 -> sc_s (pads are exactly 0, flat scan is safe)
      float mx = 0.f;
      const float* pf = &sm.u.s.G0[0][0];
      for (int i2 = tid; i2 < 3136; i2 += NT) mx = fmaxf(mx, fabsf(pf[i2]));
      for (int off = 32; off; off >>= 1) mx = fmaxf(mx, __shfl_down(mx, off));
      if ((tid & 63) == 0) sm.red[tid >> 6] = mx;
      __syncthreads();
      if (tid == 0) {
        float m2 = 0.f;
        #pragma unroll
        for (int i2 = 0; i2 < 16; ++i2) m2 = fmaxf(m2, sm.red[i2]);
        sm.sc_s = 1.f/fmaxf(m2, 1e-20f);
      }
      __syncthreads();
    }
    float (*pa)[56] = sm.u.s.G0;
    float (*pc)[56] = sm.u.s.A;
    for (int sq = 0; sq < 7; ++sq) {
      if (tid < 196) {
        const int ig = tid/14, jg = tid - ig*14;
        const int i0 = ig*4, j0 = jg*4;
        float4 acc[4];
        #pragma unroll
        for (int r = 0; r < 4; ++r) { acc[r].x = acc[r].y = acc[r].z = acc[r].w = 0.f; }
        for (int m4 = 0; m4 < 52; m4 += 4) {
          float4 b0 = *(const float4*)&pa[m4  ][j0];
          float4 b1 = *(const float4*)&pa[m4+1][j0];
          float4 b2 = *(const float4*)&pa[m4+2][j0];
          float4 b3 = *(const float4*)&pa[m4+3][j0];
          #pragma unroll
          for (int r = 0; r < 4; ++r) {
            float4 avv = *(const float4*)&pa[i0+r][m4];
            FMA4(acc[r], avv.x, b0); FMA4(acc[r], avv.y, b1);
            FMA4(acc[r], avv.z, b2); FMA4(acc[r], avv.w, b3);
          }
        }
        {
          float4 b0 = *(const float4*)&pa[52][j0];
          #pragma unroll
          for (int r = 0; r < 4; ++r) { float e = pa[i0+r][52]; FMA4(acc[r], e, b0); }
        }
        float s = sm.sc_s;  // fold normalization of pa into this store
        #pragma unroll
        for (int r = 0; r < 4; ++r) { SCL4(acc[r], s); *(float4*)&pc[i0+r][j0] = acc[r]; }
      }
      __syncthreads();
      {
        float mx = 0.f;
        const float* pf = &pc[0][0];
        for (int i2 = tid; i2 < 3136; i2 += NT) mx = fmaxf(mx, fabsf(pf[i2]));
        for (int off = 32; off; off >>= 1) mx = fmaxf(mx, __shfl_down(mx, off));
        if ((tid & 63) == 0) sm.red[tid >> 6] = mx;
        __syncthreads();
        if (tid == 0) {
          float m2 = 0.f;
          #pragma unroll
          for (int i2 = 0; i2 < 16; ++i2) m2 = fmaxf(m2, sm.red[i2]);
          sm.sc_s = 1.f/fmaxf(m2, 1e-20f);
        }
      }
      float (*tnew)[56] = pc;
      pc = (pc == sm.u.s.A) ? sm.u.s.Bq : sm.u.s.A;
      pa = tnew;
      __syncthreads();
    }
    // pv = M7 @ r  (M7 ~ G0^128 direction);  Rayleigh on fp32 G0
    if (tid < 53) {
      float s = 0.f;
      for (int j = 0; j < 53; ++j) {
        float ph = 0.618034f*(float)(j + 1);
        float rj = 0.75f + 0.5f*(ph - floorf(ph));
        s += pa[tid][j]*rj;
      }
      sm.u.s.pv[tid] = s;
    }
    __syncthreads();
    if (tid < 53) {
      float s = 0.f;
      for (int j = 0; j < 53; ++j) s += sm.u.s.G0[tid][j]*sm.u.s.pv[j];
      sm.u.s.y1[tid] = s;
    }
    __syncthreads();
    if (tid < 53) {
      float s = 0.f;
      for (int j = 0; j < 53; ++j) s += sm.u.s.G0[tid][j]*sm.u.s.y1[j];
      sm.u.s.y2[tid] = s;
    }
    __syncthreads();
    if (tid == 0) {
      float num = 0.f, den = 0.f;
      for (int i = 0; i < 53; ++i) { num += sm.u.s.y1[i]*sm.u.s.y2[i]; den += sm.u.s.y1[i]*sm.u.s.y1[i]; }
      sm.sc_ev = sqrtf(num/fmaxf(den, 1e-30f));
    }
    __syncthreads();

    // ---------- Phase 4a: attn = (S/ev) * sigmoid(|S/ev| + gate_b); emit align ----------
    {
      float inv = 1.f/sm.sc_ev;
      const size_t abase = ((size_t)b*200 + (size_t)t)*2809;
      for (int idx = tid; idx < 2809; idx += NT) {
        int i = idx/53, j = idx - i*53;
        float s = sm.S[i][j]*inv;
        float a = s*fast_sigmoid(fabsf(s) + gate_b[idx]);
        sm.S[i][j] = a;
        out_align[abase + idx] = a;
      }
    }
    __syncthreads();

    // ---------- Phase 4b: h <- attn @ v ----------
    {
      const int f0 = (tid & 31)*4;
      const int io = tid >> 5;           // 0..31
      const int i1 = io + 32;
      const bool has1 = (i1 < 53);
      float4 acc0, acc1;
      acc0.x = acc0.y = acc0.z = acc0.w = 0.f;
      acc1 = acc0;
      for (int j = 0; j < 53; ++j) {
        float4 vv = *(const float4*)&sm.v[j][f0];
        float w0 = sm.S[io][j];
        FMA4(acc0, w0, vv);
        float w1 = sm.S[has1 ? i1 : 0][j];
        FMA4(acc1, w1, vv);
      }
      *(float4*)&sm.h[io][f0] = acc0;
      if (has1) *(float4*)&sm.h[i1][f0] = acc1;
      // next-iteration B1 synchronizes these writes
    }
  }
}

// ---------------- post-scan kernels ----------------

__global__ void mean_kernel(const float* __restrict__ align, float* __restrict__ m) {
  int idx = blockIdx.x*256 + threadIdx.x;
  if (idx >= 64*2809) return;
  int b = idx/2809, c = idx - b*2809;
  const float* p = align + (size_t)b*200*2809 + c;
  float s = 0.f;
  for (int t = 0; t < 200; ++t) s += p[(size_t)t*2809];
  m[idx] = s*(1.f/200.f);
}

// xe[r][j] = sum_k (ai[r][k]*m[b][k]) * ge_w[k][j] + ge_b[j];  8 rows x 140 cols per block
__global__ void __launch_bounds__(256) xe_kernel(const float* __restrict__ align,
    const float* __restrict__ mai, const float* __restrict__ ge_w,
    const float* __restrict__ ge_b, float* __restrict__ xe) {
  __shared__ float sai[8][64];
  __shared__ float sw[64][140];
  const int tid = threadIdx.x;
  const int r0 = blockIdx.x*8;
  float4 acc0, acc1;
  acc0.x = acc0.y = acc0.z = acc0.w = 0.f;
  acc1 = acc0;
  const bool active = tid < 140;
  int rr0 = 0, cc0 = 0;
  if (active) { rr0 = (tid/35)*2; cc0 = (tid - 35*(tid/35))*4; }
  for (int k0 = 0; k0 < 2809; k0 += 64) {
    for (int l = tid; l < 512; l += 256) {
      int rr = l >> 6, kk = l & 63, k = k0 + kk;
      int r = r0 + rr;
      int bb = r/200;
      sai[rr][kk] = (k < 2809) ? align[(size_t)r*2809 + k]*mai[bb*2809 + k] : 0.f;
    }
    for (int l = tid; l < 64*140; l += 256) {
      int kk = l/140, cc = l - kk*140, k = k0 + kk;
      sw[kk][cc] = (k < 2809) ? ge_w[k*140 + cc] : 0.f;
    }
    __syncthreads();
    if (active) {
      for (int kk = 0; kk < 64; ++kk) {
        float a0 = sai[rr0][kk], a1 = sai[rr0+1][kk];
        float4 wv = *(const float4*)&sw[kk][cc0];
        FMA4(acc0, a0, wv); FMA4(acc1, a1, wv);
      }
    }
    __syncthreads();
  }
  if (active) {
    float4 gb = *(const float4*)&ge_b[cc0];
    acc0.x += gb.x; acc0.y += gb.y; acc0.z += gb.z; acc0.w += gb.w;
    acc1.x += gb.x; acc1.y += gb.y; acc1.z += gb.z; acc1.w += gb.w;
    *(float4*)&xe[(r0 + rr0)*140 + cc0]   = acc0;
    *(float4*)&xe[(r0 + rr0 + 1)*140 + cc0] = acc1;
  }
}

__global__ void bn_stats_kernel(const float* __restrict__ xe, float* __restrict__ mu,
                                float* __restrict__ var) {
  const int c = blockIdx.x, tid = threadIdx.x;
  double s = 0.0, sq = 0.0;
  for (int r = tid; r < 12800; r += 256) {
    double v = (double)xe[r*140 + c];
    s += v; sq += v*v;
  }
  for (int off = 32; off; off >>= 1) { s += __shfl_down(s, off); sq += __shfl_down(sq, off); }
  __shared__ double rs[4], rq[4];
  if ((tid & 63) == 0) { rs[tid >> 6] = s; rq[tid >> 6] = sq; }
  __syncthreads();
  if (tid == 0) {
    double S = rs[0]+rs[1]+rs[2]+rs[3], Q = rq[0]+rq[1]+rq[2]+rq[3];
    double m = S/12800.0;
    double v = Q/12800.0 - m*m;
    mu[c] = (float)m;
    var[c] = (float)fmax(v, 0.0);
  }
}

// a[r] = relu(xn[r]@ga_w1 + b1) @ ga_w2 + b2, with BN+relu fused at stage; 16 rows/block
__global__ void __launch_bounds__(256) a_kernel(const float* __restrict__ xe,
    const float* __restrict__ mu, const float* __restrict__ var,
    const float* __restrict__ bn_g, const float* __restrict__ bn_b,
    const float* __restrict__ ga_w1, const float* __restrict__ ga_b1,
    const float* __restrict__ ga_w2, const float* __restrict__ ga_b2,
    float* __restrict__ a_out) {
  __shared__ float sxn[16][140];
  __shared__ float rsum[16];
  const int tid = threadIdx.x;
  const int r0 = blockIdx.x*16;
  for (int l = tid; l < 16*140; l += 256) {
    int rr = l/140, cc = l - rr*140;
    float v = xe[(r0 + rr)*140 + cc];
    float xn = (v - mu[cc])*rsqrtf(var[cc] + 1e-5f)*bn_g[cc] + bn_b[cc];
    sxn[rr][cc] = fmaxf(xn, 0.f);
  }
  if (tid < 16) rsum[tid] = 0.f;
  __syncthreads();
  float asum[16];
  #pragma unroll
  for (int r = 0; r < 16; ++r) asum[r] = 0.f;
  for (int j = tid; j < 1404; j += 256) {
    float acc[16];
    #pragma unroll
    for (int r = 0; r < 16; ++r) acc[r] = 0.f;
    for (int k = 0; k < 140; ++k) {
      float wv = ga_w1[k*1404 + j];
      #pragma unroll
      for (int r = 0; r < 16; ++r) acc[r] += sxn[r][k]*wv;
    }
    float b1 = ga_b1[j], w2 = ga_w2[j];
    #pragma unroll
    for (int r = 0; r < 16; ++r) asum[r] += fmaxf(acc[r] + b1, 0.f)*w2;
  }
  #pragma unroll
  for (int r = 0; r < 16; ++r) atomicAdd(&rsum[r], asum[r]);
  __syncthreads();
  if (tid < 16) a_out[r0 + tid] = rsum[tid] + ga_b2[0];
}

__global__ void softmax_kernel(const float* __restrict__ a, float* __restrict__ w) {
  const int b = blockIdx.x, tid = threadIdx.x;  // 64 threads
  float mx = -1e30f;
  for (int t = tid; t < 200; t += 64) mx = fmaxf(mx, a[b*200 + t]);
  for (int off = 32; off; off >>= 1) mx = fmaxf(mx, __shfl_down(mx, off));
  mx = __shfl(mx, 0);
  float s = 0.f;
  for (int t = tid; t < 200; t += 64) { float e = __expf(a[b*200 + t] - mx); w[b*200 + t] = e; s += e; }
  for (int off = 32; off; off >>= 1) s += __shfl_down(s, off);
  s = __shfl(s, 0);
  float inv = 1.f/s;
  for (int t = tid; t < 200; t += 64) w[b*200 + t] *= inv;
}

__global__ void dnc_kernel(const float* __restrict__ align, const float* __restrict__ w,
                           float* __restrict__ dnc) {
  int idx = blockIdx.x*256 + threadIdx.x;
  if (idx >= 64*2809) return;
  int b = idx/2809, c = idx - b*2809;
  const float* p = align + (size_t)b*200*2809 + c;
  const float* pw = w + b*200;
  float s = 0.f;
  for (int t = 0; t < 200; ++t) s += p[(size_t)t*2809]*pw[t];
  dnc[idx] = s;
}

__global__ void fc_relu_kernel(const float* __restrict__ in, const float* __restrict__ wgt,
    const float* __restrict__ bias, float* __restrict__ out, int rows, int K, int N) {
  int idx = blockIdx.x*256 + threadIdx.x;
  if (idx >= rows*N) return;
  int r = idx/N, j = idx - r*N;
  const float* pi = in + (size_t)r*K;
  float s = 0.f;
  for (int k = 0; k < K; ++k) s += pi[k]*wgt[k*N + j];
  out[idx] = fmaxf(s + bias[j], 0.f);
}

__global__ void fc_kernel(const float* __restrict__ in, const float* __restrict__ wgt,
    const float* __restrict__ bias, float* __restrict__ out, int rows, int K, int N) {
  int idx = blockIdx.x*256 + threadIdx.x;
  if (idx >= rows*N) return;
  int r = idx/N, j = idx - r*N;
  const float* pi = in + (size_t)r*K;
  float s = 0.f;
  for (int k = 0; k < K; ++k) s += pi[k]*wgt[k*N + j];
  out[idx] = s + bias[j];
}

extern "C" void kernel_launch(void* const* d_in, const int* in_sizes, int n_in,
                              void* d_out, int out_size, void* d_ws, size_t ws_size,
                              hipStream_t stream) {
  (void)in_sizes; (void)n_in; (void)out_size; (void)ws_size;
  const float* x      = (const float*)d_in[0];
  const float* emb_w  = (const float*)d_in[1];
  const float* emb_b  = (const float*)d_in[2];
  const float* w_ih   = (const float*)d_in[3];
  const float* w_hh   = (const float*)d_in[4];
  const float* b_ih   = (const float*)d_in[5];
  const float* b_hh   = (const float*)d_in[6];
  const float* q_w    = (const float*)d_in[7];
  const float* q_b    = (const float*)d_in[8];
  const float* k_w    = (const float*)d_in[9];
  const float* k_b    = (const float*)d_in[10];
  const float* v_w    = (const float*)d_in[11];
  const float* v_b    = (const float*)d_in[12];
  const float* gate_b = (const float*)d_in[13];
  const float* ge_w   = (const float*)d_in[14];
  const float* ge_b   = (const float*)d_in[15];
  const float* bn_g   = (const float*)d_in[16];
  const float* bn_b   = (const float*)d_in[17];
  const float* ga_w1  = (const float*)d_in[18];
  const float* ga_b1  = (const float*)d_in[19];
  const float* ga_w2  = (const float*)d_in[20];
  const float* ga_b2  = (const float*)d_in[21];
  const float* c_w1   = (const float*)d_in[22];
  const float* c_b1   = (const float*)d_in[23];
  const float* c_w2   = (const float*)d_in[24];
  const float* c_b2   = (const float*)d_in[25];
  const float* c_w3   = (const float*)d_in[26];
  const float* c_b3   = (const float*)d_in[27];

  float* out = (float*)d_out;
  float* out_logits = out;                    // 128
  float* out_dnc    = out + 128;              // 64*2809
  float* out_align  = out + 128 + 64*2809;    // 64*200*2809

  float* ws    = (float*)d_ws;
  float* w_m   = ws;                          // 179776
  float* w_xe  = w_m + 179776;                // 1792000
  float* w_mu  = w_xe + 1792000;              // 140
  float* w_var = w_mu + 140;                  // 140
  float* w_a   = w_var + 140;                 // 12800
  float* w_w   = w_a + 12800;                 // 12800
  float* w_h1  = w_w + 12800;                 // 89856
  float* w_h2  = w_h1 + 89856;                // 44928

  const size_t shmem = sizeof(SmemScan);
  (void)hipFuncSetAttribute(reinterpret_cast<const void*>(scan_kernel),
                            hipFuncAttributeMaxDynamicSharedMemorySize, (int)shmem);

  hipLaunchKernelGGL(scan_kernel, dim3(64), dim3(1024), shmem, stream,
                     x, emb_w, emb_b, w_ih, w_hh, b_ih, b_hh,
                     q_w, q_b, k_w, k_b, v_w, v_b, gate_b, out_align);

  hipLaunchKernelGGL(mean_kernel, dim3(703), dim3(256), 0, stream, out_align, w_m);
  hipLaunchKernelGGL(xe_kernel, dim3(1600), dim3(256), 0, stream, out_align, w_m, ge_w, ge_b, w_xe);
  hipLaunchKernelGGL(bn_stats_kernel, dim3(140), dim3(256), 0, stream, w_xe, w_mu, w_var);
  hipLaunchKernelGGL(a_kernel, dim3(800), dim3(256), 0, stream,
                     w_xe, w_mu, w_var, bn_g, bn_b, ga_w1, ga_b1, ga_w2, ga_b2, w_a);
  hipLaunchKernelGGL(softmax_kernel, dim3(64), dim3(64), 0, stream, w_a, w_w);
  hipLaunchKernelGGL(dnc_kernel, dim3(703), dim3(256), 0, stream, out_align, w_w, out_dnc);
  hipLaunchKernelGGL(fc_relu_kernel, dim3(351), dim3(256), 0, stream, out_dnc, c_w1, c_b1, w_h1, 64, 2809, 1404);
  hipLaunchKernelGGL(fc_relu_kernel, dim3(176), dim3(256), 0, stream, w_h1, c_w2, c_b2, w_h2, 64, 1404, 702);
  hipLaunchKernelGGL(fc_kernel, dim3(1), dim3(128), 0, stream, w_h2, c_w3, c_b3, out_logits, 64, 702, 2);
}

// Round 2
// 35791.675 us; speedup vs baseline: 1.0732x; 1.0732x over previous
//
#include <hip/hip_runtime.h>

#define NT 1024

__device__ __forceinline__ float fast_sigmoid(float x) { return 1.f/(1.f + __expf(-x)); }
__device__ __forceinline__ float fast_tanh(float x) {
  float t = __expf(-2.f*fabsf(x));
  float y = (1.f - t)/(1.f + t);
  return copysignf(y, x);
}
__device__ __forceinline__ void acc4(float& a, float4 u, float4 v) {
  a = fmaf(u.x, v.x, a); a = fmaf(u.y, v.y, a); a = fmaf(u.z, v.z, a); a = fmaf(u.w, v.w, a);
}
#define FMA4(A_, S_, V_) do { (A_).x = fmaf((S_),(V_).x,(A_).x); (A_).y = fmaf((S_),(V_).y,(A_).y); \
                              (A_).z = fmaf((S_),(V_).z,(A_).z); (A_).w = fmaf((S_),(V_).w,(A_).w); } while(0)

// ~146 KB LDS. h/z/v rows stride 132 (h col 128 == 1.0 for bias folding).
struct alignas(16) SmemScan {
  float h[56][132];
  float z[56][132];
  float v[56][132];
  float S[56][60];
  float G0[56][60];
  float GA[56][60];
  float GB[56][60];
  float u384[384], v00[384];
  float xt[56];
  float pv[56], y1[56], y2[56];
  int   gmax[9];
  float sc_ev;
};

// ---------------- prep kernels (run once per launch) ----------------
// WhT[384][132]: col fi<128 = w_hh[fi][g]; col 128 = b_hh[g]; cols 129..131 = 0
__global__ void prep_whT(const float* __restrict__ w_hh, const float* __restrict__ b_hh,
                         float* __restrict__ WhT) {
  int idx = blockIdx.x*256 + threadIdx.x;
  if (idx >= 384*132) return;
  int g = idx/132, c = idx - g*132;
  float v = 0.f;
  if (c < 128) v = w_hh[c*384 + g];
  else if (c == 128) v = b_hh[g];
  WhT[idx] = v;
}

// WT[257][132]: rows u<129: WT[u][c] = Mhat[c][u] (c<=128), Mhat[a][b]=sum_d Wq[a][d]*Wk[b][d]
//               rows u>=129 (f=u-129): col c<128 = v_w[c][f]; col 128 = v_b[f]
__global__ void prep_wT(const float* __restrict__ q_w, const float* __restrict__ q_b,
                        const float* __restrict__ k_w, const float* __restrict__ k_b,
                        const float* __restrict__ v_w, const float* __restrict__ v_b,
                        float* __restrict__ WT) {
  int idx = blockIdx.x*256 + threadIdx.x;
  if (idx >= 257*132) return;
  int u = idx/132, c = idx - u*132;
  float val = 0.f;
  if (u < 129) {
    if (c <= 128) {
      // Mhat[a=c][b=u]
      const float* qa = (c < 128) ? (q_w + c*128) : q_b;
      const float* kb = (u < 128) ? (k_w + u*128) : k_b;
      float s = 0.f;
      for (int d = 0; d < 128; ++d) s = fmaf(qa[d], kb[d], s);
      val = s;
    }
  } else {
    int f = u - 129;
    if (c < 128) val = v_w[c*128 + f];
    else if (c == 128) val = v_b[f];
  }
  WT[idx] = val;
}

// ---------------- main scan kernel: one block per batch ----------------
__global__ void __launch_bounds__(1024, 4)
scan_kernel(const float* __restrict__ x, const float* __restrict__ emb_w,
            const float* __restrict__ emb_b, const float* __restrict__ w_ih,
            const float* __restrict__ b_ih, const float* __restrict__ WhT,
            const float* __restrict__ WT, const float* __restrict__ gate_b,
            float* __restrict__ out_align)
{
  extern __shared__ char smem_raw[];
  SmemScan& sm = *reinterpret_cast<SmemScan*>(smem_raw);
  const int b = blockIdx.x;
  const int tid = threadIdx.x;
  const int wv = tid >> 6;
  const int lane = tid & 63;

  // ---- setup: u384 = emb_w@w_ih, v00 = emb_b@w_ih + b_ih ----
  for (int j = tid; j < 384; j += NT) {
    float su = 0.f, sv = 0.f;
    for (int m = 0; m < 64; ++m) {
      float w = w_ih[m*384 + j];
      su = fmaf(emb_w[m], w, su);
      sv = fmaf(emb_b[m], w, sv);
    }
    sm.u384[j] = su;
    sm.v00[j]  = sv + b_ih[j];
  }
  // zero h/z/v fully, set h[:53][128]=1
  for (int idx = tid; idx < 56*132; idx += NT) {
    int r = idx/132, c = idx - r*132;
    float hv = (c == 128 && r < 53) ? 1.f : 0.f;
    sm.h[r][c] = hv; sm.z[r][c] = 0.f; sm.v[r][c] = 0.f;
  }
  // zero S and G buffers fully
  for (int idx = tid; idx < 56*60; idx += NT) {
    int r = idx/60, c = idx - r*60;
    sm.S[r][c] = 0.f; sm.G0[r][c] = 0.f; sm.GA[r][c] = 0.f; sm.GB[r][c] = 0.f;
  }
  __syncthreads();

  const int f  = tid & 127;
  const int c0 = tid >> 7;       // 0..7
  int  cix[7]; bool cok[7];
  #pragma unroll
  for (int i = 0; i < 7; ++i) { int cc = c0 + 8*i; cok[i] = (cc < 53); cix[i] = cok[i] ? cc : 52; }

  const float* wh0 = WhT + (size_t)f*132;
  const float* wh1 = WhT + (size_t)(128+f)*132;
  const float* wh2 = WhT + (size_t)(256+f)*132;
  const int colA = 2*f, colB = colA + 1;           // phase2 col pair (0..255)
  const float* wtA = WT + (size_t)colA*132;
  const float* wtB = WT + (size_t)colB*132;

  for (int t = 0; t < 200; ++t) {
    if (tid < 53) sm.xt[tid] = x[(b*200 + t)*53 + tid];
    __syncthreads();   // B1: x + prev-step h visible

    // ---------- Phase 1: gh = hhat@WhT (K=129, bias folded), GRU -> hnew ----------
    float a0[7], a1[7], a2[7];
    #pragma unroll
    for (int i = 0; i < 7; ++i) { a0[i] = 0.f; a1[i] = 0.f; a2[i] = 0.f; }
    for (int q = 0; q < 33; ++q) {
      float4 w0 = *(const float4*)(wh0 + 4*q);
      float4 w1 = *(const float4*)(wh1 + 4*q);
      float4 w2 = *(const float4*)(wh2 + 4*q);
      #pragma unroll
      for (int i = 0; i < 7; ++i) {
        float4 hv = *(const float4*)&sm.h[cix[i]][4*q];
        acc4(a0[i], hv, w0); acc4(a1[i], hv, w1); acc4(a2[i], hv, w2);
      }
    }
    float hnew[7];
    {
      float uf0 = sm.u384[f], uf1 = sm.u384[128+f], uf2 = sm.u384[256+f];
      float v0f0 = sm.v00[f], v0f1 = sm.v00[128+f], v0f2 = sm.v00[256+f];
      #pragma unroll
      for (int i = 0; i < 7; ++i) {
        float xs = sm.xt[cix[i]];
        float r = fast_sigmoid(fmaf(xs, uf0, v0f0) + a0[i]);
        float z = fast_sigmoid(fmaf(xs, uf1, v0f1) + a1[i]);
        float n = fast_tanh(fmaf(xs, uf2, v0f2) + fmaf(r, a2[i], 0.f));
        hnew[i] = (1.f - z)*n + z*sm.h[cix[i]][f];
      }
    }
    __syncthreads();   // B2: done reading old h
    #pragma unroll
    for (int i = 0; i < 7; ++i) if (cok[i]) sm.h[cix[i]][f] = hnew[i];
    __syncthreads();   // B3: hhat = h_new (col 128 still 1)

    // ---------- Phase 2: [z|v] = hhat @ WT^T  (257 cols, K=129) ----------
    {
      float aA[7], aB[7];
      #pragma unroll
      for (int i = 0; i < 7; ++i) { aA[i] = 0.f; aB[i] = 0.f; }
      for (int q = 0; q < 33; ++q) {
        float4 wa = *(const float4*)(wtA + 4*q);
        float4 wb = *(const float4*)(wtB + 4*q);
        #pragma unroll
        for (int i = 0; i < 7; ++i) {
          float4 hv = *(const float4*)&sm.h[cix[i]][4*q];
          acc4(aA[i], hv, wa); acc4(aB[i], hv, wb);
        }
      }
      #pragma unroll
      for (int i = 0; i < 7; ++i) if (cok[i]) {
        int c = cix[i];
        if (colA < 129) sm.z[c][colA] = aA[i]; else sm.v[c][colA-129] = aA[i];
        if (colB < 129) sm.z[c][colB] = aB[i]; else sm.v[c][colB-129] = aB[i];
      }
      // col 256 = v[:,127]
      if (tid < 53) {
        const float* wc = WT + (size_t)256*132;
        float s = 0.f;
        for (int q = 0; q < 33; ++q) {
          float4 wv4 = *(const float4*)(wc + 4*q);
          float4 hv = *(const float4*)&sm.h[tid][4*q];
          acc4(s, hv, wv4);
        }
        sm.v[tid][127] = s;
      }
    }
    __syncthreads();   // B4: z, v ready

    // ---------- Phase 3: S = tanh(z @ hhat^T)  (K=129); zero gmax ----------
    if (tid < 9) sm.gmax[tid] = 0;
    if (wv < 14 && lane < 53) {
      const int i = lane, j0 = 4*wv;
      float4 acc; acc.x = acc.y = acc.z = acc.w = 0.f;
      for (int q = 0; q < 33; ++q) {
        float4 zr = *(const float4*)&sm.z[i][4*q];
        float4 h0 = *(const float4*)&sm.h[j0  ][4*q];
        float4 h1 = *(const float4*)&sm.h[j0+1][4*q];
        float4 h2 = *(const float4*)&sm.h[j0+2][4*q];
        float4 h3 = *(const float4*)&sm.h[j0+3][4*q];
        acc4(acc.x, zr, h0); acc4(acc.y, zr, h1); acc4(acc.z, zr, h2); acc4(acc.w, zr, h3);
      }
      sm.S[i][j0  ] = fast_tanh(acc.x);
      sm.S[i][j0+1] = fast_tanh(acc.y);
      sm.S[i][j0+2] = fast_tanh(acc.z);
      sm.S[i][j0+3] = fast_tanh(acc.w);
    }
    __syncthreads();   // B5: S ready (pad rows/cols = 0)

    // ---------- G0 = S @ S^T (symmetric, eig = sigma^2), fused max ----------
    {
      float mx = 0.f;
      if (wv < 14 && lane < 53) {
        const int i = lane, j0 = 4*wv;
        float4 acc; acc.x = acc.y = acc.z = acc.w = 0.f;
        for (int q = 0; q < 14; ++q) {
          float4 sr = *(const float4*)&sm.S[i][4*q];
          float4 s0 = *(const float4*)&sm.S[j0  ][4*q];
          float4 s1 = *(const float4*)&sm.S[j0+1][4*q];
          float4 s2 = *(const float4*)&sm.S[j0+2][4*q];
          float4 s3 = *(const float4*)&sm.S[j0+3][4*q];
          acc4(acc.x, sr, s0); acc4(acc.y, sr, s1); acc4(acc.z, sr, s2); acc4(acc.w, sr, s3);
        }
        sm.G0[i][j0] = acc.x; sm.G0[i][j0+1] = acc.y;
        sm.G0[i][j0+2] = acc.z; sm.G0[i][j0+3] = acc.w;
        mx = fmaxf(fmaxf(fabsf(acc.x), fabsf(acc.y)), fmaxf(fabsf(acc.z), fabsf(acc.w)));
      }
      if (wv < 14) {
        for (int off = 32; off; off >>= 1) mx = fmaxf(mx, __shfl_down(mx, off));
        if (lane == 0) atomicMax(&sm.gmax[0], __float_as_int(mx));
      }
    }
    __syncthreads();

    // ---------- 7 normalized squarings of symmetric matrix ----------
    float (*pa)[60] = sm.G0;
    float (*pc)[60] = sm.GA;
    for (int k = 0; k < 7; ++k) {
      float mx = 0.f;
      if (wv < 14 && lane < 53) {
        float s = 1.f/fmaxf(__int_as_float(sm.gmax[k]), 1e-20f);
        const int i = lane, j0 = 4*wv;
        float4 acc; acc.x = acc.y = acc.z = acc.w = 0.f;
        for (int q = 0; q < 14; ++q) {
          float4 ar = *(const float4*)&pa[i][4*q];
          float4 b0 = *(const float4*)&pa[j0  ][4*q];
          float4 b1 = *(const float4*)&pa[j0+1][4*q];
          float4 b2 = *(const float4*)&pa[j0+2][4*q];
          float4 b3 = *(const float4*)&pa[j0+3][4*q];
          acc4(acc.x, ar, b0); acc4(acc.y, ar, b1); acc4(acc.z, ar, b2); acc4(acc.w, ar, b3);
        }
        float s2 = s*s;
        acc.x *= s2; acc.y *= s2; acc.z *= s2; acc.w *= s2;
        pc[i][j0] = acc.x; pc[i][j0+1] = acc.y; pc[i][j0+2] = acc.z; pc[i][j0+3] = acc.w;
        mx = fmaxf(fmaxf(fabsf(acc.x), fabsf(acc.y)), fmaxf(fabsf(acc.z), fabsf(acc.w)));
      }
      if (wv < 14) {
        for (int off = 32; off; off >>= 1) mx = fmaxf(mx, __shfl_down(mx, off));
        if (lane == 0) atomicMax(&sm.gmax[k+1], __float_as_int(mx));
      }
      __syncthreads();
      float (*tn)[60] = pc;
      pc = (pc == sm.GA) ? sm.GB : sm.GA;
      pa = tn;
    }

    // ---------- pv = pa @ r ; y1 = G0 pv ; y2 = G0 y1 ; Rayleigh ----------
    if (tid < 53) {
      float s = 0.f;
      for (int j = 0; j < 53; ++j) {
        float ph = 0.618034f*(float)(j + 1);
        float rj = 0.75f + 0.5f*(ph - floorf(ph));
        s = fmaf(pa[tid][j], rj, s);
      }
      sm.pv[tid] = s;
    }
    __syncthreads();
    if (tid < 53) {
      float s = 0.f;
      for (int j = 0; j < 53; ++j) s = fmaf(sm.G0[tid][j], sm.pv[j], s);
      sm.y1[tid] = s;
    }
    __syncthreads();
    if (tid < 53) {
      float s = 0.f;
      for (int j = 0; j < 53; ++j) s = fmaf(sm.G0[tid][j], sm.y1[j], s);
      sm.y2[tid] = s;
    }
    __syncthreads();
    if (tid < 64) {
      float yа = (tid < 53) ? sm.y1[tid] : 0.f;
      float yb = (tid < 53) ? sm.y2[tid] : 0.f;
      float num = yа*yb, den = yа*yа;
      for (int off = 32; off; off >>= 1) { num += __shfl_down(num, off); den += __shfl_down(den, off); }
      if (tid == 0) sm.sc_ev = sqrtf(num/fmaxf(den, 1e-30f));
    }
    __syncthreads();

    // ---------- Phase 4a: attn = (S/ev)*sigmoid(|S/ev| + gate_b); write align ----------
    {
      float inv = 1.f/sm.sc_ev;
      const size_t abase = ((size_t)b*200 + (size_t)t)*2809;
      for (int idx = tid; idx < 2809; idx += NT) {
        int i = idx/53, j = idx - i*53;
        float s = sm.S[i][j]*inv;
        float a = s*fast_sigmoid(fabsf(s) + gate_b[idx]);
        sm.S[i][j] = a;
        out_align[abase + idx] = a;
      }
    }
    __syncthreads();

    // ---------- Phase 4b: h <- attn @ v (writes cols 0..127 only) ----------
    {
      const int f0 = (tid & 31)*4;
      const int io = tid >> 5;           // 0..31
      const int i1 = io + 32;
      const bool has1 = (i1 < 53);
      float4 acc0, acc1;
      acc0.x = acc0.y = acc0.z = acc0.w = 0.f;
      acc1 = acc0;
      for (int q = 0; q < 14; ++q) {
        float4 s0 = *(const float4*)&sm.S[io][4*q];
        float4 s1 = *(const float4*)&sm.S[has1 ? i1 : 0][4*q];
        int j = 4*q;
        float4 v0 = *(const float4*)&sm.v[j  ][f0];
        float4 v1 = *(const float4*)&sm.v[j+1][f0];
        float4 v2 = *(const float4*)&sm.v[j+2][f0];
        float4 v3 = *(const float4*)&sm.v[j+3][f0];
        FMA4(acc0, s0.x, v0); FMA4(acc0, s0.y, v1); FMA4(acc0, s0.z, v2); FMA4(acc0, s0.w, v3);
        FMA4(acc1, s1.x, v0); FMA4(acc1, s1.y, v1); FMA4(acc1, s1.z, v2); FMA4(acc1, s1.w, v3);
      }
      *(float4*)&sm.h[io][f0] = acc0;
      if (has1) *(float4*)&sm.h[i1][f0] = acc1;
      // next-iteration B1 synchronizes these writes
    }
  }
}

// ---------------- post-scan kernels (unchanged) ----------------

__global__ void mean_kernel(const float* __restrict__ align, float* __restrict__ m) {
  int idx = blockIdx.x*256 + threadIdx.x;
  if (idx >= 64*2809) return;
  int b = idx/2809, c = idx - b*2809;
  const float* p = align + (size_t)b*200*2809 + c;
  float s = 0.f;
  for (int t = 0; t < 200; ++t) s += p[(size_t)t*2809];
  m[idx] = s*(1.f/200.f);
}

__global__ void __launch_bounds__(256) xe_kernel(const float* __restrict__ align,
    const float* __restrict__ mai, const float* __restrict__ ge_w,
    const float* __restrict__ ge_b, float* __restrict__ xe) {
  __shared__ float sai[8][64];
  __shared__ float sw[64][140];
  const int tid = threadIdx.x;
  const int r0 = blockIdx.x*8;
  float4 acc0, acc1;
  acc0.x = acc0.y = acc0.z = acc0.w = 0.f;
  acc1 = acc0;
  const bool active = tid < 140;
  int rr0 = 0, cc0 = 0;
  if (active) { rr0 = (tid/35)*2; cc0 = (tid - 35*(tid/35))*4; }
  for (int k0 = 0; k0 < 2809; k0 += 64) {
    for (int l = tid; l < 512; l += 256) {
      int rr = l >> 6, kk = l & 63, k = k0 + kk;
      int r = r0 + rr;
      int bb = r/200;
      sai[rr][kk] = (k < 2809) ? align[(size_t)r*2809 + k]*mai[bb*2809 + k] : 0.f;
    }
    for (int l = tid; l < 64*140; l += 256) {
      int kk = l/140, cc = l - kk*140, k = k0 + kk;
      sw[kk][cc] = (k < 2809) ? ge_w[k*140 + cc] : 0.f;
    }
    __syncthreads();
    if (active) {
      for (int kk = 0; kk < 64; ++kk) {
        float a0 = sai[rr0][kk], a1 = sai[rr0+1][kk];
        float4 wv = *(const float4*)&sw[kk][cc0];
        FMA4(acc0, a0, wv); FMA4(acc1, a1, wv);
      }
    }
    __syncthreads();
  }
  if (active) {
    float4 gb = *(const float4*)&ge_b[cc0];
    acc0.x += gb.x; acc0.y += gb.y; acc0.z += gb.z; acc0.w += gb.w;
    acc1.x += gb.x; acc1.y += gb.y; acc1.z += gb.z; acc1.w += gb.w;
    *(float4*)&xe[(r0 + rr0)*140 + cc0]   = acc0;
    *(float4*)&xe[(r0 + rr0 + 1)*140 + cc0] = acc1;
  }
}

__global__ void bn_stats_kernel(const float* __restrict__ xe, float* __restrict__ mu,
                                float* __restrict__ var) {
  const int c = blockIdx.x, tid = threadIdx.x;
  double s = 0.0, sq = 0.0;
  for (int r = tid; r < 12800; r += 256) {
    double v = (double)xe[r*140 + c];
    s += v; sq += v*v;
  }
  for (int off = 32; off; off >>= 1) { s += __shfl_down(s, off); sq += __shfl_down(sq, off); }
  __shared__ double rs[4], rq[4];
  if ((tid & 63) == 0) { rs[tid >> 6] = s; rq[tid >> 6] = sq; }
  __syncthreads();
  if (tid == 0) {
    double S = rs[0]+rs[1]+rs[2]+rs[3], Q = rq[0]+rq[1]+rq[2]+rq[3];
    double m = S/12800.0;
    double v = Q/12800.0 - m*m;
    mu[c] = (float)m;
    var[c] = (float)fmax(v, 0.0);
  }
}

__global__ void __launch_bounds__(256) a_kernel(const float* __restrict__ xe,
    const float* __restrict__ mu, const float* __restrict__ var,
    const float* __restrict__ bn_g, const float* __restrict__ bn_b,
    const float* __restrict__ ga_w1, const float* __restrict__ ga_b1,
    const float* __restrict__ ga_w2, const float* __restrict__ ga_b2,
    float* __restrict__ a_out) {
  __shared__ float sxn[16][140];
  __shared__ float rsum[16];
  const int tid = threadIdx.x;
  const int r0 = blockIdx.x*16;
  for (int l = tid; l < 16*140; l += 256) {
    int rr = l/140, cc = l - rr*140;
    float v = xe[(r0 + rr)*140 + cc];
    float xn = (v - mu[cc])*rsqrtf(var[cc] + 1e-5f)*bn_g[cc] + bn_b[cc];
    sxn[rr][cc] = fmaxf(xn, 0.f);
  }
  if (tid < 16) rsum[tid] = 0.f;
  __syncthreads();
  float asum[16];
  #pragma unroll
  for (int r = 0; r < 16; ++r) asum[r] = 0.f;
  for (int j = tid; j < 1404; j += 256) {
    float acc[16];
    #pragma unroll
    for (int r = 0; r < 16; ++r) acc[r] = 0.f;
    for (int k = 0; k < 140; ++k) {
      float wv = ga_w1[k*1404 + j];
      #pragma unroll
      for (int r = 0; r < 16; ++r) acc[r] += sxn[r][k]*wv;
    }
    float b1 = ga_b1[j], w2 = ga_w2[j];
    #pragma unroll
    for (int r = 0; r < 16; ++r) asum[r] += fmaxf(acc[r] + b1, 0.f)*w2;
  }
  #pragma unroll
  for (int r = 0; r < 16; ++r) atomicAdd(&rsum[r], asum[r]);
  __syncthreads();
  if (tid < 16) a_out[r0 + tid] = rsum[tid] + ga_b2[0];
}

__global__ void softmax_kernel(const float* __restrict__ a, float* __restrict__ w) {
  const int b = blockIdx.x, tid = threadIdx.x;  // 64 threads
  float mx = -1e30f;
  for (int t = tid; t < 200; t += 64) mx = fmaxf(mx, a[b*200 + t]);
  for (int off = 32; off; off >>= 1) mx = fmaxf(mx, __shfl_down(mx, off));
  mx = __shfl(mx, 0);
  float s = 0.f;
  for (int t = tid; t < 200; t += 64) { float e = __expf(a[b*200 + t] - mx); w[b*200 + t] = e; s += e; }
  for (int off = 32; off; off >>= 1) s += __shfl_down(s, off);
  s = __shfl(s, 0);
  float inv = 1.f/s;
  for (int t = tid; t < 200; t += 64) w[b*200 + t] *= inv;
}

__global__ void dnc_kernel(const float* __restrict__ align, const float* __restrict__ w,
                           float* __restrict__ dnc) {
  int idx = blockIdx.x*256 + threadIdx.x;
  if (idx >= 64*2809) return;
  int b = idx/2809, c = idx - b*2809;
  const float* p = align + (size_t)b*200*2809 + c;
  const float* pw = w + b*200;
  float s = 0.f;
  for (int t = 0; t < 200; ++t) s += p[(size_t)t*2809]*pw[t];
  dnc[idx] = s;
}

__global__ void fc_relu_kernel(const float* __restrict__ in, const float* __restrict__ wgt,
    const float* __restrict__ bias, float* __restrict__ out, int rows, int K, int N) {
  int idx = blockIdx.x*256 + threadIdx.x;
  if (idx >= rows*N) return;
  int r = idx/N, j = idx - r*N;
  const float* pi = in + (size_t)r*K;
  float s = 0.f;
  for (int k = 0; k < K; ++k) s += pi[k]*wgt[k*N + j];
  out[idx] = fmaxf(s + bias[j], 0.f);
}

__global__ void fc_kernel(const float* __restrict__ in, const float* __restrict__ wgt,
    const float* __restrict__ bias, float* __restrict__ out, int rows, int K, int N) {
  int idx = blockIdx.x*256 + threadIdx.x;
  if (idx >= rows*N) return;
  int r = idx/N, j = idx - r*N;
  const float* pi = in + (size_t)r*K;
  float s = 0.f;
  for (int k = 0; k < K; ++k) s += pi[k]*wgt[k*N + j];
  out[idx] = s + bias[j];
}

extern "C" void kernel_launch(void* const* d_in, const int* in_sizes, int n_in,
                              void* d_out, int out_size, void* d_ws, size_t ws_size,
                              hipStream_t stream) {
  (void)in_sizes; (void)n_in; (void)out_size; (void)ws_size;
  const float* x      = (const float*)d_in[0];
  const float* emb_w  = (const float*)d_in[1];
  const float* emb_b  = (const float*)d_in[2];
  const float* w_ih   = (const float*)d_in[3];
  const float* w_hh   = (const float*)d_in[4];
  const float* b_ih   = (const float*)d_in[5];
  const float* b_hh   = (const float*)d_in[6];
  const float* q_w    = (const float*)d_in[7];
  const float* q_b    = (const float*)d_in[8];
  const float* k_w    = (const float*)d_in[9];
  const float* k_b    = (const float*)d_in[10];
  const float* v_w    = (const float*)d_in[11];
  const float* v_b    = (const float*)d_in[12];
  const float* gate_b = (const float*)d_in[13];
  const float* ge_w   = (const float*)d_in[14];
  const float* ge_b   = (const float*)d_in[15];
  const float* bn_g   = (const float*)d_in[16];
  const float* bn_b   = (const float*)d_in[17];
  const float* ga_w1  = (const float*)d_in[18];
  const float* ga_b1  = (const float*)d_in[19];
  const float* ga_w2  = (const float*)d_in[20];
  const float* ga_b2  = (const float*)d_in[21];
  const float* c_w1   = (const float*)d_in[22];
  const float* c_b1   = (const float*)d_in[23];
  const float* c_w2   = (const float*)d_in[24];
  const float* c_b2   = (const float*)d_in[25];
  const float* c_w3   = (const float*)d_in[26];
  const float* c_b3   = (const float*)d_in[27];

  float* out = (float*)d_out;
  float* out_logits = out;                    // 128
  float* out_dnc    = out + 128;              // 64*2809
  float* out_align  = out + 128 + 64*2809;    // 64*200*2809

  float* ws    = (float*)d_ws;
  float* w_WhT = ws;                          // 384*132 = 50688
  float* w_WT  = w_WhT + 50688;               // 257*132 = 33924
  float* w_m   = w_WT + 33924;                // 179776
  float* w_xe  = w_m + 179776;                // 1792000
  float* w_mu  = w_xe + 1792000;              // 140
  float* w_var = w_mu + 140;                  // 140
  float* w_a   = w_var + 140;                 // 12800
  float* w_w   = w_a + 12800;                 // 12800
  float* w_h1  = w_w + 12800;                 // 89856
  float* w_h2  = w_h1 + 89856;                // 44928

  hipLaunchKernelGGL(prep_whT, dim3((384*132 + 255)/256), dim3(256), 0, stream, w_hh, b_hh, w_WhT);
  hipLaunchKernelGGL(prep_wT, dim3((257*132 + 255)/256), dim3(256), 0, stream,
                     q_w, q_b, k_w, k_b, v_w, v_b, w_WT);

  const size_t shmem = sizeof(SmemScan);
  (void)hipFuncSetAttribute(reinterpret_cast<const void*>(scan_kernel),
                            hipFuncAttributeMaxDynamicSharedMemorySize, (int)shmem);

  hipLaunchKernelGGL(scan_kernel, dim3(64), dim3(1024), shmem, stream,
                     x, emb_w, emb_b, w_ih, b_ih, w_WhT, w_WT, gate_b, out_align);

  hipLaunchKernelGGL(mean_kernel, dim3(703), dim3(256), 0, stream, out_align, w_m);
  hipLaunchKernelGGL(xe_kernel, dim3(1600), dim3(256), 0, stream, out_align, w_m, ge_w, ge_b, w_xe);
  hipLaunchKernelGGL(bn_stats_kernel, dim3(140), dim3(256), 0, stream, w_xe, w_mu, w_var);
  hipLaunchKernelGGL(a_kernel, dim3(800), dim3(256), 0, stream,
                     w_xe, w_mu, w_var, bn_g, bn_b, ga_w1, ga_b1, ga_w2, ga_b2, w_a);
  hipLaunchKernelGGL(softmax_kernel, dim3(64), dim3(64), 0, stream, w_a, w_w);
  hipLaunchKernelGGL(dnc_kernel, dim3(703), dim3(256), 0, stream, out_align, w_w, out_dnc);
  hipLaunchKernelGGL(fc_relu_kernel, dim3(351), dim3(256), 0, stream, out_dnc, c_w1, c_b1, w_h1, 64, 2809, 1404);
  hipLaunchKernelGGL(fc_relu_kernel, dim3(176), dim3(256), 0, stream, w_h1, c_w2, c_b2, w_h2, 64, 1404, 702);
  hipLaunchKernelGGL(fc_kernel, dim3(1), dim3(128), 0, stream, w_h2, c_w3, c_b3, out_logits, 64, 702, 2);
}